// Round 11
// baseline (21773.593 us; speedup 1.0000x reference)
//
#include <hip/hip_runtime.h>

// TemporalMambaBlock: B=2,T=16,H=W=28,C=192; D_inner=384, d_state=16, dt_rank=12, d_conv=4
#define NSEQ 1568
#define TDIM 16
#define CDIM 192
#define DIN  384
#define SDIM 16
#define RNK  12
#define XZW  768
#define DBLW 44
#define HW784 784
#define FGRID 1024   // fused grid: 4 blocks/CU x 256 CUs; LDS allows 5 -> 25% residency margin

// padded LDS strides (halves): row stride dwords mod 32 == 4 -> b128 quad reads 2-way (free)
#define XNP  200   // xn rows (192 + 8 pad)
#define DINP 392   // u / z rows (384 + 8)
#define DBLP 48    // dbl rows (44 -> 48, f32)

// packed-weight tiling. Fragment layout (lane, j=0..7):
//   packed[((nt*KT + kt)*64 + lane)*8 + j] = W[kt*32 + (lane>>4)*8 + j][nt*16 + (lane&15)]
// Operand-symmetric: usable as B (B[k=quad*8+j][n=l16]) or as A (A[m=l16][k=quad*8+j] = W^T).
#define NT_IN 48
#define KT_IN 6
#define NT_OUT 12
#define KT_OUT 12
#define NT_XP 3
#define KT_XP 12
#define GRP_IN  (NT_IN*KT_IN*64)    // 18432 groups of 8
#define GRP_OUT (NT_OUT*KT_OUT*64)  // 9216
#define GRP_XP  (NT_XP*KT_XP*64)    // 2304
#define OFF_OUT (GRP_IN*8)
#define OFF_XP  (OFF_OUT + GRP_OUT*8)
#define WS_ELEMS (OFF_XP + GRP_XP*8)            // 239616 u16
#define WS_NEED ((size_t)WS_ELEMS * 2)          // 479232 bytes

#define IN_EL  (CDIM*XZW)   // 147456
#define OUT_EL (DIN*CDIM)   // 73728
#define XP_EL  (GRP_XP*8)   // 18432 (packed space, incl. pad)
#define PACK_TOT (IN_EL + OUT_EL + XP_EL)       // 239616 <= FGRID*384

typedef unsigned short u16;
typedef unsigned int   u32;
typedef __attribute__((ext_vector_type(8))) short short8;
typedef __attribute__((ext_vector_type(4))) float f32x4;
typedef __attribute__((ext_vector_type(2))) unsigned int u32x2;

#define LOG2E 1.44269504f
#define LN2   0.69314718f

// Persistent monotone arrival counter for the software grid barrier.
// Each kernel execution adds exactly FGRID; window k = my/FGRID identifies the
// execution (calls are sequential on one stream; rocprof replays are whole-grid).
__device__ unsigned g_arrive = 0;

// fallback home for packed weights (correct but ~+100 MB HBM/call vs d_ws —
// measured rounds 7/8; used only if ws_size too small).
__device__ __align__(16) u16 g_ws[WS_ELEMS];

__device__ __forceinline__ float bf2f(u16 u) {
  union { u32 i; float f; } c; c.i = ((u32)u) << 16; return c.f;
}
__device__ __forceinline__ u16 f2bf(float f) {   // round-to-nearest-even
  union { float f; u32 i; } c; c.f = f;
  u32 i = c.i;
  i += 0x7FFFu + ((i >> 16) & 1u);
  return (u16)(i >> 16);
}

__device__ __forceinline__ float ex2(float x) {
#if __has_builtin(__builtin_amdgcn_exp2f)
  return __builtin_amdgcn_exp2f(x);
#else
  return exp2f(x);
#endif
}
__device__ __forceinline__ float lg2(float x) {
#if __has_builtin(__builtin_amdgcn_logf)
  return __builtin_amdgcn_logf(x);
#else
  return log2f(x);
#endif
}
__device__ __forceinline__ float frcp(float x) {
#if __has_builtin(__builtin_amdgcn_rcpf)
  return __builtin_amdgcn_rcpf(x);
#else
  return 1.0f / x;
#endif
}
__device__ __forceinline__ float sigmoid_f(float s) {       // 1/(1+e^-s)
  return frcp(1.0f + ex2(-LOG2E * s));
}
__device__ __forceinline__ float softplus_f(float a) {      // log(1+e^a), stable
  return fmaxf(a, 0.f) + LN2 * lg2(1.0f + ex2(-LOG2E * fabsf(a)));
}

template<bool B16>
__device__ __forceinline__ float ldg(const void* p, int i) {
  if (B16) return bf2f(((const u16*)p)[i]);
  return ((const float*)p)[i];
}
template<bool B16>
__device__ __forceinline__ void stg(void* p, int i, float v) {
  if (B16) ((u16*)p)[i] = f2bf(v);
  else     ((float*)p)[i] = v;
}

// dtype probe: bf16 data has plausible exponents at even u16 slots; f32 read
// as u16 gives mantissa noise. (Rounds 2-10: selects the f32 path.)
__device__ __forceinline__ bool probe_bf16(const void* x) {
  const u16* xu = (const u16*)x;
  int plaus = 0;
  #pragma unroll
  for (int k = 0; k < 32; ++k) {
    u16 v = xu[2*k];
    int e = (v >> 7) & 0xFF;
    plaus += ((e >= 100 && e <= 140) || v == 0) ? 1 : 0;
  }
  return plaus >= 16;
}

// ---------------- weight packing: element-wise, coalesced reads -------------
template<bool B16>
__device__ __forceinline__ void pack_body(u16* __restrict__ ws,
                                          const void* in_w, const void* out_w,
                                          const void* xp_w, int e) {
  if (e < IN_EL) {
    int k = e / XZW, n = e - k*XZW;
    int nt = n >> 4, l16 = n & 15, kt = k >> 5, q8 = (k & 31) >> 3, j = k & 7;
    int lane = q8*16 + l16;
    ws[((nt*KT_IN + kt)*64 + lane)*8 + j] = f2bf(ldg<B16>(in_w, e));
  } else if (e < IN_EL + OUT_EL) {
    int ee = e - IN_EL;
    int k = ee / CDIM, n = ee - k*CDIM;
    int nt = n >> 4, l16 = n & 15, kt = k >> 5, q8 = (k & 31) >> 3, j = k & 7;
    int lane = q8*16 + l16;
    ws[OFF_OUT + ((nt*KT_OUT + kt)*64 + lane)*8 + j] = f2bf(ldg<B16>(out_w, ee));
  } else if (e < PACK_TOT) {             // xp: iterate packed space (handles pad)
    int ee = e - IN_EL - OUT_EL;
    int gg = ee >> 3, j = ee & 7;
    int lane = gg & 63, kt = (gg >> 6) % KT_XP, nt = gg / (64*KT_XP);
    int k = kt*32 + (lane >> 4)*8 + j, n = nt*16 + (lane & 15);
    ws[OFF_XP + ee] = f2bf(n < DBLW ? ldg<B16>(xp_w, k*DBLW + n) : 0.f);
  }
}

// ---------------- fused MFMA body (one sequence) ----------------------------
struct Smem {
  union {                 // lifetimes disjoint: xn P1-P2, dbl P4-P5
    u16   xn [TDIM*XNP];  // rmsnormed, padded             6400 B
    float __align__(16) dbl[TDIM*DBLP];  // x_proj out     3072 B
  };
  u16   u  [TDIM*DINP];   // u -> uc (in-place), padded   12544 B
  u16   z  [TDIM*DINP];   // z -> gated y (in-place)      12544 B
};                        // total 31,488 B -> 5 blocks/CU possible

template<bool B16>
__device__ __forceinline__ void body(
    Smem& sm, const u16* __restrict__ ws, int n,
    const void* __restrict__ x,        const void* __restrict__ norm_w,
    const void* __restrict__ conv_w,   const void* __restrict__ conv_b,
    const void* __restrict__ dt_proj_w,const void* __restrict__ dt_proj_b,
    const void* __restrict__ A_log,    const void* __restrict__ Dp,
    void* __restrict__ out)
{
  const int tid  = threadIdx.x;
  const int wid  = tid >> 6;
  const int lane = tid & 63;
  const int quad = lane >> 4;
  const int l16  = lane & 15;
  const int b  = n / HW784;
  const int hw = n - b * HW784;

  // ---- P1: RMSNorm straight from global (192 = 3 x 64 lanes) -> xn ----
  {
    const int c0 = lane, c1 = lane + 64, c2 = lane + 128;
    float nw0 = ldg<B16>(norm_w, c0), nw1 = ldg<B16>(norm_w, c1), nw2 = ldg<B16>(norm_w, c2);
    for (int t = wid; t < TDIM; t += 6) {
      int base = ((b*TDIM + t)*HW784 + hw)*CDIM;
      float v0 = ldg<B16>(x, base + c0);
      float v1 = ldg<B16>(x, base + c1);
      float v2 = ldg<B16>(x, base + c2);
      float ss = v0*v0 + v1*v1 + v2*v2;
      #pragma unroll
      for (int off = 32; off > 0; off >>= 1) ss += __shfl_xor(ss, off, 64);
      float rs = rsqrtf(ss * (1.0f/CDIM) + 1e-6f);
      sm.xn[t*XNP + c0] = f2bf(v0 * rs * nw0);
      sm.xn[t*XNP + c1] = f2bf(v1 * rs * nw1);
      sm.xn[t*XNP + c2] = f2bf(v2 * rs * nw2);
    }
  }
  __syncthreads();

  // ---- P2: in_proj via MFMA, swapped operands (W^T as A, Xn^T as B) ----
  // D[m=channel][n=t]: lane holds 4 consecutive channels at t=l16 -> b64 LDS write.
  {
    short8 xfr[KT_IN];   // B operand: Xn[t=l16][kt*32+quad*8..+7]
    #pragma unroll
    for (int kt = 0; kt < KT_IN; ++kt)
      xfr[kt] = *(const short8*)(sm.xn + l16*XNP + kt*32 + quad*8);
    #pragma unroll
    for (int g = 0; g < 2; ++g) {
      f32x4 acc[4];
      #pragma unroll
      for (int i = 0; i < 4; ++i) acc[i] = (f32x4)0.f;
      #pragma unroll
      for (int kt = 0; kt < KT_IN; ++kt) {
        #pragma unroll
        for (int i = 0; i < 4; ++i) {
          int ntg = wid*8 + g*4 + i;
          short8 wfr = *(const short8*)(ws + ((ntg*KT_IN + kt)*64 + lane)*8);
          acc[i] = __builtin_amdgcn_mfma_f32_16x16x32_bf16(wfr, xfr[kt], acc[i], 0, 0, 0);
        }
      }
      #pragma unroll
      for (int i = 0; i < 4; ++i) {
        int ntg = wid*8 + g*4 + i;
        u16* dst  = (ntg < 24) ? sm.u : sm.z;
        int col0  = ((ntg < 24) ? ntg*16 : (ntg-24)*16) + quad*4;  // 4 consecutive channels
        u32x2 o;
        o[0] = ((u32)f2bf(acc[i][1]) << 16) | f2bf(acc[i][0]);
        o[1] = ((u32)f2bf(acc[i][3]) << 16) | f2bf(acc[i][2]);
        *(u32x2*)(dst + l16*DINP + col0) = o;    // t=l16 row, b64 write
      }
    }
  }
  __syncthreads();

  // ---- P3: causal depthwise conv (k=4) + SiLU, in place (no reg carry:
  //      uvr[16] carried across P4 spilled to scratch => +53 MB HBM, round 9) ----
  {
    const int d = tid;
    float cw0 = ldg<B16>(conv_w, d*4+0), cw1 = ldg<B16>(conv_w, d*4+1);
    float cw2 = ldg<B16>(conv_w, d*4+2), cw3 = ldg<B16>(conv_w, d*4+3);
    float cbias = ldg<B16>(conv_b, d);
    float um1 = 0.f, um2 = 0.f, um3 = 0.f;
    #pragma unroll
    for (int t = 0; t < TDIM; ++t) {
      float cur = bf2f(sm.u[t*DINP + d]);
      float s = cbias + cur*cw3 + um1*cw2 + um2*cw1 + um3*cw0;
      um3 = um2; um2 = um1; um1 = cur;
      sm.u[t*DINP + d] = f2bf(s * sigmoid_f(s));
    }
  }

  // hoist scan parameters (waves 3..5 idle in P4 overlap these loads)
  float wd[RNK];
  float dt_bias = ldg<B16>(dt_proj_b, tid);
  #pragma unroll
  for (int r = 0; r < RNK; ++r) wd[r] = ldg<B16>(dt_proj_w, r*DIN + tid);
  float Dv = ldg<B16>(Dp, tid);
  // geometric-A detection: A[s] = -exp(A_log[s]); geo iff A[s] == (s+1)*A[0]
  float a2 = -LOG2E * ex2(LOG2E * ldg<B16>(A_log, tid*SDIM + 0));  // LOG2E*A[0]
  bool geo = true;
  #pragma unroll
  for (int s = 1; s < SDIM; ++s) {
    float as = -LOG2E * ex2(LOG2E * ldg<B16>(A_log, tid*SDIM + s));
    geo = geo && (fabsf(as - (float)(s+1)*a2) <= 1e-4f * fabsf(as) + 1e-30f);
  }
  __syncthreads();

  // ---- P4: x_proj via MFMA, swapped operands (xp_w^T as A, uc^T as B) ----
  if (wid < 3) {
    f32x4 acc = (f32x4)0.f;
    #pragma unroll
    for (int kt = 0; kt < KT_XP; ++kt) {
      short8 ufr = *(const short8*)(sm.u + l16*DINP + kt*32 + quad*8);
      short8 wfr = *(const short8*)(ws + OFF_XP + ((wid*KT_XP + kt)*64 + lane)*8);
      acc = __builtin_amdgcn_mfma_f32_16x16x32_bf16(wfr, ufr, acc, 0, 0, 0);
    }
    // dbl[t=l16][feat = wid*16 + quad*4 + r]: 4 consecutive f32 -> b128 write
    *(f32x4*)(sm.dbl + l16*DBLP + wid*16 + quad*4) = acc;
  }
  __syncthreads();

  // ---- P5: dt_proj + softplus + selective scan + D skip + SiLU(z) gating ----
  {
    const int d = tid;
    float h[SDIM];
    #pragma unroll
    for (int s = 0; s < SDIM; ++s) h[s] = 0.f;
    if (geo) {
      for (int t = 0; t < TDIM; ++t) {
        const float* row = sm.dbl + t*DBLP;
        f32x4 d0 = *(const f32x4*)(row + 0);
        f32x4 d1 = *(const f32x4*)(row + 4);
        f32x4 d2 = *(const f32x4*)(row + 8);
        float a = dt_bias
          + d0[0]*wd[0] + d0[1]*wd[1] + d0[2]*wd[2]  + d0[3]*wd[3]
          + d1[0]*wd[4] + d1[1]*wd[5] + d1[2]*wd[6]  + d1[3]*wd[7]
          + d2[0]*wd[8] + d2[1]*wd[9] + d2[2]*wd[10] + d2[3]*wd[11];
        float dtv = softplus_f(a);
        float uv  = bf2f(sm.u[t*DINP + d]);
        float du  = dtv * uv;
        float q = ex2(dtv * a2);               // dA[0] = exp(dt*A[0])
        float Pq[SDIM];                        // Pq[s] = q^(s+1), log-depth tree
        Pq[0] = q;        Pq[1] = q*q;         Pq[2] = Pq[1]*q;     Pq[3] = Pq[1]*Pq[1];
        Pq[4] = Pq[3]*q;  Pq[5] = Pq[3]*Pq[1]; Pq[6] = Pq[3]*Pq[2]; Pq[7] = Pq[3]*Pq[3];
        Pq[8] = Pq[7]*q;  Pq[9] = Pq[7]*Pq[1]; Pq[10]= Pq[7]*Pq[2]; Pq[11]= Pq[7]*Pq[3];
        Pq[12]= Pq[7]*Pq[4]; Pq[13]= Pq[7]*Pq[5]; Pq[14]= Pq[7]*Pq[6]; Pq[15]= Pq[7]*Pq[7];
        float y = 0.f;
        #pragma unroll
        for (int g = 0; g < 4; ++g) {
          f32x4 Bv = *(const f32x4*)(row + 12 + 4*g);
          f32x4 Cv = *(const f32x4*)(row + 28 + 4*g);
          #pragma unroll
          for (int j = 0; j < 4; ++j) {
            int s = 4*g + j;
            h[s] = h[s]*Pq[s] + du*Bv[j];
            y += h[s]*Cv[j];
          }
        }
        y += uv * Dv;
        float zv = bf2f(sm.z[t*DINP + d]);
        sm.z[t*DINP + d] = f2bf(y * (zv * sigmoid_f(zv)));
      }
    } else {
      // cold path (A_log not geometric): reloads A each step
      for (int t = 0; t < TDIM; ++t) {
        const float* row = sm.dbl + t*DBLP;
        float a = dt_bias;
        #pragma unroll
        for (int r = 0; r < RNK; ++r) a += row[r] * wd[r];
        float dtv = softplus_f(a);
        float uv  = bf2f(sm.u[t*DINP + d]);
        float du  = dtv * uv;
        float y = 0.f;
        #pragma unroll
        for (int s = 0; s < SDIM; ++s) {
          float As = -LOG2E * ex2(LOG2E * ldg<B16>(A_log, d*SDIM + s));
          float dA = ex2(dtv * As);
          h[s] = h[s]*dA + du * row[12 + s];
          y += h[s] * row[28 + s];
        }
        y += uv * Dv;
        float zv = bf2f(sm.z[t*DINP + d]);
        sm.z[t*DINP + d] = f2bf(y * (zv * sigmoid_f(zv)));
      }
    }
  }
  __syncthreads();

  // ---- P6: out_proj via MFMA (Y as A, W as B) + residual ----
  // D[m=t][n=out-channel]; epilogue 4 B/lane, 4 segments/instruction (proven clean).
  {
    f32x4 acc[2];
    acc[0] = (f32x4)0.f; acc[1] = (f32x4)0.f;
    #pragma unroll
    for (int kt = 0; kt < KT_OUT; ++kt) {
      short8 yfr = *(const short8*)(sm.z + l16*DINP + kt*32 + quad*8);
      #pragma unroll
      for (int i = 0; i < 2; ++i) {
        int ntg = wid*2 + i;
        short8 wfr = *(const short8*)(ws + OFF_OUT + ((ntg*KT_OUT + kt)*64 + lane)*8);
        acc[i] = __builtin_amdgcn_mfma_f32_16x16x32_bf16(yfr, wfr, acc[i], 0, 0, 0);
      }
    }
    #pragma unroll
    for (int i = 0; i < 2; ++i) {
      int col = (wid*2 + i)*16 + l16;
      #pragma unroll
      for (int r = 0; r < 4; ++r) {
        int row = quad*4 + r;
        int gi = ((b*TDIM + row)*HW784 + hw)*CDIM + col;
        float o = ldg<B16>(x, gi) + acc[i][r];
        stg<B16>(out, gi, o);
      }
    }
  }
  // no trailing barrier needed: next iteration's P1 writes xn (disjoint from
  // P6's reads), and the P1->P2 barrier orders everything else.
}

// ---------------- fused single kernel: pack + SW grid barrier + mamba -------
__launch_bounds__(384, 6)   // VGPR cap 85; actual ~44 -> LDS is the residency limiter (5/CU)
__global__ void mamba_fused1(
    u16* __restrict__ ws,
    const void* __restrict__ x,        const void* __restrict__ norm_w,
    const void* __restrict__ in_w,     const void* __restrict__ conv_w,
    const void* __restrict__ conv_b,   const void* __restrict__ xp_w,
    const void* __restrict__ dt_w,     const void* __restrict__ dt_b,
    const void* __restrict__ A_log,    const void* __restrict__ Dp,
    const void* __restrict__ out_w,    void* __restrict__ out)
{
  __shared__ Smem sm;
  __shared__ int s_timeout;
  const bool b16 = probe_bf16(x);

  // ---- pack phase: 1024*384 threads cover PACK_TOT in one pass ----
  int e = blockIdx.x * 384 + threadIdx.x;
  if (e < PACK_TOT) {
    if (b16) pack_body<true >(ws, in_w, out_w, xp_w, e);
    else     pack_body<false>(ws, in_w, out_w, xp_w, e);
  }
  __threadfence();            // device-scope release of ws writes (L2 writeback)
  __syncthreads();

  // ---- software grid barrier (monotone window; deadlock-proof via timeout) ----
  if (threadIdx.x == 0) {
    unsigned my = __hip_atomic_fetch_add(&g_arrive, 1u, __ATOMIC_RELEASE,
                                         __HIP_MEMORY_SCOPE_AGENT);
    unsigned target = (my / (unsigned)FGRID + 1u) * (unsigned)FGRID;
    int to = 1;
    for (int i = 0; i < 65536; ++i) {   // ~14 ms worst case
      if (__hip_atomic_load(&g_arrive, __ATOMIC_RELAXED,
                            __HIP_MEMORY_SCOPE_AGENT) >= target) { to = 0; break; }
      __builtin_amdgcn_s_sleep(8);
    }
    (void)__hip_atomic_load(&g_arrive, __ATOMIC_ACQUIRE,
                            __HIP_MEMORY_SCOPE_AGENT);   // L2 invalidate (acquire)
    s_timeout = to;
  }
  __syncthreads();
  if (s_timeout) {            // pathological scheduling: self-pack (idempotent)
    for (int e2 = threadIdx.x; e2 < PACK_TOT; e2 += 384) {
      if (b16) pack_body<true >(ws, in_w, out_w, xp_w, e2);
      else     pack_body<false>(ws, in_w, out_w, xp_w, e2);
    }
    __threadfence();
    __syncthreads();
  }
  __threadfence();

  // ---- mamba phase: sequences blockIdx, blockIdx+1024 ----
  for (int n = blockIdx.x; n < NSEQ; n += FGRID) {
    if (b16) body<true >(sm, ws, n, x, norm_w, conv_w, conv_b, dt_w, dt_b, A_log, Dp, out);
    else     body<false>(sm, ws, n, x, norm_w, conv_w, conv_b, dt_w, dt_b, A_log, Dp, out);
    __syncthreads();
  }
}

// ---------------- fallback: proven 2-kernel g_ws path (rounds 7/8) ----------
__global__ void pack_w_g(const void* __restrict__ x, const void* __restrict__ in_w,
                         const void* __restrict__ out_w, const void* __restrict__ xp_w) {
  int e = blockIdx.x * blockDim.x + threadIdx.x;
  if (e < PACK_TOT) {
    if (probe_bf16(x)) pack_body<true >(g_ws, in_w, out_w, xp_w, e);
    else               pack_body<false>(g_ws, in_w, out_w, xp_w, e);
  }
}

__launch_bounds__(384, 6)
__global__ void mamba_mfma_g(
    const void* __restrict__ x,        const void* __restrict__ norm_w,
    const void* __restrict__ conv_w,   const void* __restrict__ conv_b,
    const void* __restrict__ dt_w,     const void* __restrict__ dt_b,
    const void* __restrict__ A_log,    const void* __restrict__ Dp,
    void* __restrict__ out)
{
  __shared__ Smem sm;
  if (probe_bf16(x))
    body<true >(sm, g_ws, blockIdx.x, x, norm_w, conv_w, conv_b, dt_w, dt_b, A_log, Dp, out);
  else
    body<false>(sm, g_ws, blockIdx.x, x, norm_w, conv_w, conv_b, dt_w, dt_b, A_log, Dp, out);
}

extern "C" void kernel_launch(void* const* d_in, const int* in_sizes, int n_in,
                              void* d_out, int out_size, void* d_ws, size_t ws_size,
                              hipStream_t stream) {
  if (ws_size >= WS_NEED) {
    mamba_fused1<<<FGRID, 384, 0, stream>>>(
        (u16*)d_ws,
        d_in[0], d_in[1], d_in[2], d_in[3], d_in[4], d_in[5],
        d_in[6], d_in[7], d_in[8], d_in[9], d_in[10], d_out);
  } else {
    pack_w_g<<<(PACK_TOT + 255) / 256, 256, 0, stream>>>(
        d_in[0], d_in[2], d_in[10], d_in[5]);
    mamba_mfma_g<<<NSEQ, 384, 0, stream>>>(
        d_in[0], d_in[1], d_in[3], d_in[4],
        d_in[6], d_in[7], d_in[8], d_in[9], d_out);
  }
}